// Round 12
// baseline (43.260 us; speedup 1.0000x reference)
//
#include <hip/hip_runtime.h>
#include <math.h>
#include <limits.h>

#pragma clang fp contract(off)

#define N_ANCH 17064
#define BATCH  16
#define NGT    32
#define EPSF   1e-6f

#define NPB     512          // phaseB blocks, ids [0, 512)  (dispatched FIRST)
#define NSTREAM 1536         // stream blocks, ids [512, 2048); grid = 2048 = co-resident
#define SSTRIDE (NSTREAM * 256)   // 393216 float4s
#define L2E 1.44269504088896340736f
#define LN2 0.69314718055994530942f

// float4 cumulative level bounds (16*81*HW/4)
#define C1   4147200
#define C2   5184000
#define C3   5443200
#define C4   5510592
#define TOT4 5528736

__device__ __forceinline__ float fexp2(float x){ return __builtin_amdgcn_exp2f(x); }
__device__ __forceinline__ float flog2(float x){ return __builtin_amdgcn_logf(x); }
__device__ __forceinline__ float frcp (float x){ return __builtin_amdgcn_rcpf(x); }

// ---------- geometry ----------
struct Geo { int lvl; int j; int HW; float px; float py; };

__device__ __forceinline__ Geo geom(int n) {
  Geo g;
  if (n < 12800)      { g.lvl=0; g.j=n;       g.HW=12800; g.px=(float)((g.j & 127)*8 + 4);   g.py=(float)((g.j >> 7)*8 + 4);   }
  else if (n < 16000) { g.lvl=1; g.j=n-12800; g.HW=3200;  g.px=(float)((g.j & 63)*16 + 8);   g.py=(float)((g.j >> 6)*16 + 8);  }
  else if (n < 16800) { g.lvl=2; g.j=n-16000; g.HW=800;   g.px=(float)((g.j & 31)*32 + 16);  g.py=(float)((g.j >> 5)*32 + 16); }
  else if (n < 17008) { g.lvl=3; g.j=n-16800; g.HW=208;   g.px=(float)((g.j & 15)*64 + 32);  g.py=(float)((g.j >> 4)*64 + 32); }
  else                { g.lvl=4; g.j=n-17008; g.HW=56;    g.px=(float)((g.j & 7)*128 + 64);  g.py=(float)((g.j >> 3)*128 + 64);}
  return g;
}

// ---------- min-key top-k helpers (key = 2*kl, smaller = larger overlap) ----------
__device__ __forceinline__ bool bet(float av, int ai, float bv, int bi) {
  return (av < bv) || (av == bv && ai < bi);
}

__device__ __forceinline__ void insert3min(float* v, int* i, float nv, int ni) {
  if (nv < v[0])      { v[2]=v[1]; i[2]=i[1]; v[1]=v[0]; i[1]=i[0]; v[0]=nv; i[0]=ni; }
  else if (nv < v[1]) { v[2]=v[1]; i[2]=i[1]; v[1]=nv; i[1]=ni; }
  else                { v[2]=nv; i[2]=ni; }
}

__device__ __forceinline__ void insert3tie(float* v, int* i, float nv, int ni) {
  if (!bet(nv, ni, v[2], i[2])) return;
  if (bet(nv, ni, v[0], i[0]))      { v[2]=v[1]; i[2]=i[1]; v[1]=v[0]; i[1]=i[0]; v[0]=nv; i[0]=ni; }
  else if (bet(nv, ni, v[1], i[1])) { v[2]=v[1]; i[2]=i[1]; v[1]=nv; i[1]=ni; }
  else                              { v[2]=nv; i[2]=ni; }
}

// negative-class focal term: 0.75 * sigmoid(x)^2 * softplus(x)
__device__ __forceinline__ float negterm(float x) {
  float ax = fabsf(x);
  float e  = fexp2(ax * -L2E);          // exp(-|x|)
  float r  = frcp(1.0f + e);
  float p  = (x >= 0.0f) ? r : e * r;   // sigmoid(x)
  float sp = fmaxf(x, 0.0f) + flog2(1.0f + e) * LN2;   // softplus(x)
  return 0.75f * (p * p) * sp;
}

__device__ __forceinline__ float negterm4(float4 f) {
  return ((negterm(f.x) + negterm(f.y)) + (negterm(f.z) + negterm(f.w)));
}

// address select for a global float4 index across the 5 level tensors
__device__ __forceinline__ const float4* lvl_addr(int i, const float4* s0, const float4* s1,
                                                  const float4* s2, const float4* s3,
                                                  const float4* s4) {
  if (i < C1)      return s0 + i;
  else if (i < C2) return s1 + (i - C1);
  else if (i < C3) return s2 + (i - C2);
  else if (i < C4) return s3 + (i - C3);
  else             return s4 + (i - C4);
}

// ---------- megaK: heterogeneous grid, NO cross-block protocol ----------
// blocks [0, NPB):            per-(b,g) top3(ov1) + top1(ov2) -> win[]   (first!)
// blocks [NPB, NPB+NSTREAM):  label-free stream of cls logits -> part[]
__global__ __launch_bounds__(256) void megaK(const float4* __restrict__ gtb,
                                             const float4* __restrict__ s0,
                                             const float4* __restrict__ s1,
                                             const float4* __restrict__ s2,
                                             const float4* __restrict__ s3,
                                             const float4* __restrict__ s4,
                                             int4* __restrict__ win,
                                             float* __restrict__ part) {
  __shared__ float sv[256 * 3];
  __shared__ int   si[256 * 3];
  __shared__ float tv[256];
  __shared__ int   ti[256];
  __shared__ float sh[256];

  int t = threadIdx.x;
  if (blockIdx.x >= NPB) {
    // ---------------- label-free cls stream: 5-deep preloaded batches ----------------
    // Iterations 0..9 are provably level-0 for every thread (9*S + S-1 < C1).
    int sb = blockIdx.x - NPB;
    int i = sb * 256 + t;
    float acc0 = 0.0f, acc1 = 0.0f;
    #pragma unroll
    for (int r = 0; r < 2; ++r) {
      float4 v0 = s0[i];
      float4 v1 = s0[i +     SSTRIDE];
      float4 v2 = s0[i + 2 * SSTRIDE];
      float4 v3 = s0[i + 3 * SSTRIDE];
      float4 v4 = s0[i + 4 * SSTRIDE];
      acc0 += negterm4(v0);
      acc1 += negterm4(v1);
      acc0 += negterm4(v2);
      acc1 += negterm4(v3);
      acc0 += negterm4(v4);
      i += 5 * SSTRIDE;
    }
    // tail: up to 5 more iterations, masked batch (addresses clamped, fully unrolled)
    {
      int  j0 = i,               j1 = i + SSTRIDE,     j2 = i + 2 * SSTRIDE;
      int  j3 = i + 3 * SSTRIDE, j4 = i + 4 * SSTRIDE;
      bool m0 = j0 < TOT4, m1 = j1 < TOT4, m2 = j2 < TOT4, m3 = j3 < TOT4, m4 = j4 < TOT4;
      const float4* p0 = lvl_addr(m0 ? j0 : 0, s0, s1, s2, s3, s4);
      const float4* p1 = lvl_addr(m1 ? j1 : 0, s0, s1, s2, s3, s4);
      const float4* p2 = lvl_addr(m2 ? j2 : 0, s0, s1, s2, s3, s4);
      const float4* p3 = lvl_addr(m3 ? j3 : 0, s0, s1, s2, s3, s4);
      const float4* p4 = lvl_addr(m4 ? j4 : 0, s0, s1, s2, s3, s4);
      float4 v0 = *p0; float4 v1 = *p1; float4 v2 = *p2; float4 v3 = *p3; float4 v4 = *p4;
      acc0 += m0 ? negterm4(v0) : 0.0f;
      acc1 += m1 ? negterm4(v1) : 0.0f;
      acc0 += m2 ? negterm4(v2) : 0.0f;
      acc1 += m3 ? negterm4(v3) : 0.0f;
      acc0 += m4 ? negterm4(v4) : 0.0f;
    }
    sh[t] = acc0 + acc1;
    __syncthreads();
    #pragma unroll
    for (int off = 128; off > 0; off >>= 1) {
      if (t < off) sh[t] += sh[t + off];
      __syncthreads();
    }
    if (t == 0) part[sb] = sh[0];
    return;
  }

  // ---------------- phaseB ----------------
  int blk = blockIdx.x;
  int b = blk >> 5, g = blk & 31;
  float4 GB = gtb[b * NGT + g];
  float c1x = (GB.x + GB.z) * 0.5f, c1y = (GB.y + GB.w) * 0.5f;
  float w1 = GB.z - GB.x + EPSF, h1 = GB.w - GB.y + EPSF;
  float w1s = w1 * w1, h1s = h1 * h1;
  float iw = 1.0f / w1s, ih = 1.0f / h1s;
  float iws = iw + ih;
  float Lg = logf(w1s) + logf(h1s);
  float Ay = 4.0f * ih;
  float Axc = 4.0f * iw;

  float v1[3] = {INFINITY, INFINITY, INFINITY};
  int   i1[3] = {INT_MAX, INT_MAX, INT_MAX};
  float v2 = INFINITY; int i2 = INT_MAX;

  #define DO_LEVEL(BASE, LGW, H, STRIDE, RF) do {                             \
    const int W_ = 1 << (LGW);                                                \
    float w2a = (RF) + 1e-6f;          float w2sa = w2a * w2a;                \
    float w2b = (RF) * 0.9f + 1e-6f;   float w2sb = w2b * w2b;                \
    float K1 = w2sa * iws + Lg - 2.0f * logf(w2sa) - 2.0f;                    \
    float K2 = w2sb * iws + Lg - 2.0f * logf(w2sb) - 2.0f;                    \
    int col = t & (W_ - 1);                                                   \
    float px = (float)(col * (STRIDE) + (STRIDE) / 2);                        \
    float dx = c1x - px;                                                      \
    float kx1 = Axc * dx * dx + K1;                                           \
    float kx2 = Axc * dx * dx + K2;                                           \
    int rstep = 256 >> (LGW);                                                 \
    for (int row = t >> (LGW); row < (H); row += rstep) {                     \
      float py = (float)(row * (STRIDE) + (STRIDE) / 2);                      \
      float dy = c1y - py;                                                    \
      float dy2 = dy * dy;                                                    \
      float k1 = fmaf(Ay, dy2, kx1);                                          \
      float k2 = fmaf(Ay, dy2, kx2);                                          \
      int n = (BASE) + (row << (LGW)) + col;                                  \
      if (k1 < v1[2]) insert3min(v1, i1, k1, n);                              \
      if (k2 < v2) { v2 = k2; i2 = n; }                                       \
    }                                                                         \
  } while (0)

  DO_LEVEL(0,     7, 100,   8,  45.5f);
  DO_LEVEL(12800, 6,  50,  16, 133.5f);
  DO_LEVEL(16000, 5,  25,  32, 213.5f);
  DO_LEVEL(16800, 4,  13,  64, 277.5f);
  DO_LEVEL(17008, 3,   7, 128, 405.5f);
  #undef DO_LEVEL

  sv[t*3+0] = v1[0]; sv[t*3+1] = v1[1]; sv[t*3+2] = v1[2];
  si[t*3+0] = i1[0]; si[t*3+1] = i1[1]; si[t*3+2] = i1[2];
  tv[t] = v2; ti[t] = i2;
  __syncthreads();
  for (int off = 128; off > 0; off >>= 1) {
    if (t < off) {
      #pragma unroll
      for (int k = 0; k < 3; ++k)
        insert3tie(&sv[t * 3], &si[t * 3], sv[(t + off) * 3 + k], si[(t + off) * 3 + k]);
      if (bet(tv[t + off], ti[t + off], tv[t], ti[t])) { tv[t] = tv[t + off]; ti[t] = ti[t + off]; }
    }
    __syncthreads();
  }
  if (t == 0) win[blk] = make_int4(si[0], si[1], si[2], ti[0]);
}

// ---------- resolveK: dedup claims, box/ctr losses, cls corrections, finalize ----------
__global__ __launch_bounds__(1024) void resolveK(
    const int* __restrict__ win, const float4* __restrict__ gtb, const int* __restrict__ glab,
    const float* __restrict__ c0, const float* __restrict__ c1, const float* __restrict__ c2,
    const float* __restrict__ c3, const float* __restrict__ c4,
    const float* __restrict__ bb0, const float* __restrict__ bb1, const float* __restrict__ bb2,
    const float* __restrict__ bb3, const float* __restrict__ bb4,
    const float* __restrict__ ct0, const float* __restrict__ ct1, const float* __restrict__ ct2,
    const float* __restrict__ ct3, const float* __restrict__ ct4,
    const float* __restrict__ part, float* __restrict__ out) {
  int t = threadIdx.x;
  __shared__ unsigned int keys[NPB * 4];
  // key = ((b*32768 + n) << 6) | pri,  pri = tier*32 + g  (tier2 beats tier1, then larger g)
  for (int k = t; k < NPB * 4; k += 1024) {
    int blk = k >> 2, s = k & 3;
    int b = blk >> 5, g = blk & 31;
    int n = win[k];
    unsigned int pri = ((s == 3) ? 32u : 0u) + (unsigned int)g;
    keys[k] = (((unsigned int)(b * 32768 + n)) << 6) | pri;
  }
  __syncthreads();

  double a_cls = 0.0, a_pos = 0.0, a_ctr = 0.0, a_diou = 0.0, a_cbce = 0.0;

  // stream partials (fixed order per thread -> deterministic)
  for (int i = t; i < NSTREAM; i += 1024) a_cls += (double)part[i];

  const float* clsA[5] = {c0, c1, c2, c3, c4};
  const float* bbA[5]  = {bb0, bb1, bb2, bb3, bb4};
  const float* ctA[5]  = {ct0, ct1, ct2, ct3, ct4};

  for (int k = t; k < NPB * 4; k += 1024) {
    unsigned int me = keys[k];
    unsigned int bn = me >> 6;
    int b = (int)(bn >> 15);
    int base = b * 128;                 // this image's 128 candidate slots
    bool alive = true;
    #pragma unroll 4
    for (int j = 0; j < 128; ++j) {
      unsigned int o = keys[base + j];
      if ((o >> 6) == bn && o > me) { alive = false; }
    }
    if (!alive) continue;

    int n = (int)(bn & 32767u);
    int g = (int)(me & 31u);
    int lab = glab[b * NGT + g];
    float4 gb = gtb[b * NGT + g];
    Geo G = geom(n);

    const float* bb = bbA[G.lvl];
    const float* ct = ctA[G.lvl];
    const float* cp = clsA[G.lvl];

    const float* bp = bb + b * 4 * G.HW + G.j;
    float f0 = bp[0];
    float f1 = bp[G.HW];
    float f2 = bp[2 * G.HW];
    float f3 = bp[3 * G.HW];
    float fo = ct[b * G.HW + G.j];
    float xc = cp[((size_t)(b * 81 + lab)) * G.HW + G.j];

    // cls correction: posterm - negterm at the target logit
    {
      float ax = fabsf(xc);
      float e  = fexp2(ax * -L2E);
      float r  = frcp(1.0f + e);
      float p  = (xc >= 0.0f) ? r : e * r;
      float sp = fmaxf(xc, 0.0f) + flog2(1.0f + e) * LN2;
      float neg = 0.75f * (p * p) * sp;
      float omp = 1.0f - p;
      float pos = 0.25f * (omp * omp) * (sp - xc);
      a_cls += (double)(pos - neg);
    }

    float tx = G.px - gb.x, ty = G.py - gb.y, tz = gb.z - G.px, tw = gb.w - G.py;

    float lr_min = fminf(tx, tz), lr_max = fmaxf(tx, tz);
    float tb_min = fminf(ty, tw), tb_max = fmaxf(ty, tw);
    float prod = (lr_min / lr_max) * (tb_min / tb_max);
    float ctrt = sqrtf(fmaxf(prod, 0.0f));

    float pb0 = G.px - f0, pb1 = G.py - f1, pb2 = G.px + f2, pb3 = G.py + f3;
    float tb0 = G.px - tx, tb1 = G.py - ty, tb2 = G.px + tz, tb3 = G.py + tw;

    float ltx = fmaxf(pb0, tb0), lty = fmaxf(pb1, tb1);
    float rbx = fminf(pb2, tb2), rby = fminf(pb3, tb3);
    float whx = fmaxf(rbx - ltx, 0.0f), why = fmaxf(rby - lty, 0.0f);
    float ovl = whx * why;
    float ap = (pb2 - pb0) * (pb3 - pb1);
    float ag = (tb2 - tb0) * (tb3 - tb1);
    float ious = ovl / (ap + ag - ovl + EPSF);
    float eltx = fminf(pb0, tb0), elty = fminf(pb1, tb1);
    float erbx = fmaxf(pb2, tb2), erby = fmaxf(pb3, tb3);
    float ewx = fmaxf(erbx - eltx, 0.0f), ewy = fmaxf(erby - elty, 0.0f);
    float c2v = ewx * ewx + ewy * ewy + EPSF;
    float sx = pb0 + pb2 - tb0 - tb2;
    float sy = pb1 + pb3 - tb1 - tb3;
    float rho2 = (sx * sx + sy * sy) * 0.25f;
    float dl = 1.0f - (ious - rho2 / c2v);

    a_pos  += 1.0;
    a_ctr  += (double)ctrt;
    a_diou += (double)(dl * ctrt);
    a_cbce += (double)(fmaxf(fo, 0.0f) - fo * ctrt + log1pf(expf(-fabsf(fo))));
  }

  __shared__ double r0[1024], r1[1024], r2[1024], r3[1024], r4[1024];
  r0[t] = a_cls; r1[t] = a_pos; r2[t] = a_ctr; r3[t] = a_diou; r4[t] = a_cbce;
  __syncthreads();
  #pragma unroll
  for (int off = 512; off > 0; off >>= 1) {
    if (t < off) {
      r0[t] += r0[t + off]; r1[t] += r1[t + off]; r2[t] += r2[t + off];
      r3[t] += r3[t + off]; r4[t] += r4[t + off];
    }
    __syncthreads();
  }
  if (t == 0) {
    double np_ = r1[0] > 1.0 ? r1[0] : 1.0;
    double dn  = r2[0] > 1e-6 ? r2[0] : 1e-6;
    out[0] = (float)(r0[0] / np_);
    out[1] = (float)(r3[0] / dn);
    out[2] = (float)(r4[0] / np_);
  }
}

extern "C" void kernel_launch(void* const* d_in, const int* in_sizes, int n_in,
                              void* d_out, int out_size, void* d_ws, size_t ws_size,
                              hipStream_t stream) {
  (void)in_sizes; (void)n_in; (void)out_size; (void)ws_size;
  const float* cls[5] = {(const float*)d_in[0],  (const float*)d_in[3],  (const float*)d_in[6],
                         (const float*)d_in[9],  (const float*)d_in[12]};
  const float* bbx[5] = {(const float*)d_in[1],  (const float*)d_in[4],  (const float*)d_in[7],
                         (const float*)d_in[10], (const float*)d_in[13]};
  const float* ctr[5] = {(const float*)d_in[2],  (const float*)d_in[5],  (const float*)d_in[8],
                         (const float*)d_in[11], (const float*)d_in[14]};
  const float4* gtb = (const float4*)d_in[15];
  const int* glab = (const int*)d_in[16];

  char* ws = (char*)d_ws;
  int4*  win  = (int4*)ws;                       // 512 * 16 B = 8 KB
  float* part = (float*)(ws + NPB * 16);         // 1536 floats

  megaK<<<NPB + NSTREAM, 256, 0, stream>>>(gtb,
                                           (const float4*)cls[0], (const float4*)cls[1],
                                           (const float4*)cls[2], (const float4*)cls[3],
                                           (const float4*)cls[4],
                                           win, part);
  resolveK<<<1, 1024, 0, stream>>>((const int*)win, gtb, glab,
                                   cls[0], cls[1], cls[2], cls[3], cls[4],
                                   bbx[0], bbx[1], bbx[2], bbx[3], bbx[4],
                                   ctr[0], ctr[1], ctr[2], ctr[3], ctr[4],
                                   part, (float*)d_out);
}

// Round 13
// 41.454 us; speedup vs baseline: 1.0436x; 1.0436x over previous
//
#include <hip/hip_runtime.h>
#include <math.h>
#include <limits.h>

#pragma clang fp contract(off)

#define N_ANCH 17064
#define BATCH  16
#define NGT    32
#define EPSF   1e-6f

#define NPB     512          // phaseB blocks, ids [0, 512)  (dispatched FIRST)
#define NSTREAM 1536         // stream blocks, ids [512, 2048); grid = 2048 = co-resident
#define SSTRIDE (NSTREAM * 256)   // 393216 float4s
#define SUBN    96                // stream blocks per sub-counter (1536/16)
#define L2E 1.44269504088896340736f
#define LN2 0.69314718055994530942f

// float4 cumulative level bounds (16*81*HW/4)
#define C1   4147200
#define C2   5184000
#define C3   5443200
#define C4   5510592
#define TOT4 5528736

// counter ints: [0..15] done_img, [16..31] done_sub, [32] done_glb
#define CTR_IMG 0
#define CTR_SUB 16
#define CTR_GLB 32

__device__ __forceinline__ float fexp2(float x){ return __builtin_amdgcn_exp2f(x); }
__device__ __forceinline__ float flog2(float x){ return __builtin_amdgcn_logf(x); }
__device__ __forceinline__ float frcp (float x){ return __builtin_amdgcn_rcpf(x); }

typedef float f4v __attribute__((ext_vector_type(4)));

__device__ __forceinline__ f4v ntload4(const float4* p) {
  return __builtin_nontemporal_load((const f4v*)p);
}

// agent-scope relaxed atomics: per-address coherence, no cache-wide invalidate
__device__ __forceinline__ void astore_u32(unsigned int* p, unsigned int v) {
  __hip_atomic_store(p, v, __ATOMIC_RELAXED, __HIP_MEMORY_SCOPE_AGENT);
}
__device__ __forceinline__ unsigned int aload_u32(const unsigned int* p) {
  return __hip_atomic_load(p, __ATOMIC_RELAXED, __HIP_MEMORY_SCOPE_AGENT);
}
__device__ __forceinline__ void astore_u64(unsigned long long* p, unsigned long long v) {
  __hip_atomic_store(p, v, __ATOMIC_RELAXED, __HIP_MEMORY_SCOPE_AGENT);
}
__device__ __forceinline__ unsigned long long aload_u64(const unsigned long long* p) {
  return __hip_atomic_load(p, __ATOMIC_RELAXED, __HIP_MEMORY_SCOPE_AGENT);
}
#define VMCNT0() asm volatile("s_waitcnt vmcnt(0)" ::: "memory")

// ---------- geometry ----------
struct Geo { int lvl; int j; int HW; float px; float py; };

__device__ __forceinline__ Geo geom(int n) {
  Geo g;
  if (n < 12800)      { g.lvl=0; g.j=n;       g.HW=12800; g.px=(float)((g.j & 127)*8 + 4);   g.py=(float)((g.j >> 7)*8 + 4);   }
  else if (n < 16000) { g.lvl=1; g.j=n-12800; g.HW=3200;  g.px=(float)((g.j & 63)*16 + 8);   g.py=(float)((g.j >> 6)*16 + 8);  }
  else if (n < 16800) { g.lvl=2; g.j=n-16000; g.HW=800;   g.px=(float)((g.j & 31)*32 + 16);  g.py=(float)((g.j >> 5)*32 + 16); }
  else if (n < 17008) { g.lvl=3; g.j=n-16800; g.HW=208;   g.px=(float)((g.j & 15)*64 + 32);  g.py=(float)((g.j >> 4)*64 + 32); }
  else                { g.lvl=4; g.j=n-17008; g.HW=56;    g.px=(float)((g.j & 7)*128 + 64);  g.py=(float)((g.j >> 3)*128 + 64);}
  return g;
}

// ---------- min-key top-k helpers ----------
__device__ __forceinline__ bool bet(float av, int ai, float bv, int bi) {
  return (av < bv) || (av == bv && ai < bi);
}

__device__ __forceinline__ void insert3min(float* v, int* i, float nv, int ni) {
  if (nv < v[0])      { v[2]=v[1]; i[2]=i[1]; v[1]=v[0]; i[1]=i[0]; v[0]=nv; i[0]=ni; }
  else if (nv < v[1]) { v[2]=v[1]; i[2]=i[1]; v[1]=nv; i[1]=ni; }
  else                { v[2]=nv; i[2]=ni; }
}

__device__ __forceinline__ void insert3tie(float* v, int* i, float nv, int ni) {
  if (!bet(nv, ni, v[2], i[2])) return;
  if (bet(nv, ni, v[0], i[0]))      { v[2]=v[1]; i[2]=i[1]; v[1]=v[0]; i[1]=i[0]; v[0]=nv; i[0]=ni; }
  else if (bet(nv, ni, v[1], i[1])) { v[2]=v[1]; i[2]=i[1]; v[1]=nv; i[1]=ni; }
  else                              { v[2]=nv; i[2]=ni; }
}

// negative-class focal term: 0.75 * sigmoid(x)^2 * softplus(x)
__device__ __forceinline__ float negterm(float x) {
  float ax = fabsf(x);
  float e  = fexp2(ax * -L2E);
  float r  = frcp(1.0f + e);
  float p  = (x >= 0.0f) ? r : e * r;
  float sp = fmaxf(x, 0.0f) + flog2(1.0f + e) * LN2;
  return 0.75f * (p * p) * sp;
}

__device__ __forceinline__ float negterm4(f4v f) {
  return ((negterm(f[0]) + negterm(f[1])) + (negterm(f[2]) + negterm(f[3])));
}

// address select across the 5 level tensors
__device__ __forceinline__ const float4* lvl_addr(int i, const float4* s0, const float4* s1,
                                                  const float4* s2, const float4* s3,
                                                  const float4* s4) {
  if (i < C1)      return s0 + i;
  else if (i < C2) return s1 + (i - C1);
  else if (i < C3) return s2 + (i - C2);
  else if (i < C4) return s3 + (i - C3);
  else             return s4 + (i - C4);
}

__global__ void zeroK(int* __restrict__ ctr) {
  int i = threadIdx.x;
  if (i < 33) ctr[i] = 0;
}

// final combine: R = 96 shared doubles; fixed-order deterministic sum
__device__ __forceinline__ void final_combine(const unsigned long long* __restrict__ bpart,
                                              const unsigned long long* __restrict__ gsum,
                                              float* __restrict__ out,
                                              double* R, int t) {
  if (t < 16) {
    R[t]      = __longlong_as_double(aload_u64(&gsum[t]));
    R[16+t]   = __longlong_as_double(aload_u64(&bpart[t*5+0]));
    R[32+t]   = __longlong_as_double(aload_u64(&bpart[t*5+1]));
    R[48+t]   = __longlong_as_double(aload_u64(&bpart[t*5+2]));
    R[64+t]   = __longlong_as_double(aload_u64(&bpart[t*5+3]));
    R[80+t]   = __longlong_as_double(aload_u64(&bpart[t*5+4]));
  }
  __syncthreads();
  if (t == 0) {
    double sc = 0.0, sp = 0.0, sct = 0.0, sdi = 0.0, scb = 0.0;
    for (int i = 0; i < 16; ++i) sc += R[i];
    for (int i = 0; i < 16; ++i) {
      sc  += R[16+i];
      sp  += R[32+i];
      sct += R[48+i];
      sdi += R[64+i];
      scb += R[80+i];
    }
    double np_ = sp > 1.0 ? sp : 1.0;
    double dn  = sct > 1e-6 ? sct : 1e-6;
    out[0] = (float)(sc / np_);
    out[1] = (float)(sdi / dn);
    out[2] = (float)(scb / np_);
  }
}

// ---------- fusedK: grid 2048, all co-resident, no spinning ----------
// blocks [0, NPB):            phaseB per (b,g); 32nd finisher per image resolves it
// blocks [NPB, 2048):         label-free cls stream; 96th finisher per subgroup
//                             pre-reduces its 96 partials into gsum[g]
// 32nd bump of done_glb (16 subgroups + 16 images) runs final combine.
__global__ __launch_bounds__(256) void fusedK(
    const float4* __restrict__ gtb, const int* __restrict__ glab,
    const float* __restrict__ c0, const float* __restrict__ c1, const float* __restrict__ c2,
    const float* __restrict__ c3, const float* __restrict__ c4,
    const float* __restrict__ bb0, const float* __restrict__ bb1, const float* __restrict__ bb2,
    const float* __restrict__ bb3, const float* __restrict__ bb4,
    const float* __restrict__ ct0, const float* __restrict__ ct1, const float* __restrict__ ct2,
    const float* __restrict__ ct3, const float* __restrict__ ct4,
    unsigned int* __restrict__ win, unsigned int* __restrict__ part,
    unsigned long long* __restrict__ bpart, unsigned long long* __restrict__ gsum,
    int* __restrict__ ctr, float* __restrict__ out) {
  __shared__ char smem[9216];          // overlaid per-phase
  __shared__ int sflag, sflag2;

  int t  = threadIdx.x;
  int bi = blockIdx.x;

  if (bi >= NPB) {
    // ---------------- cls stream: NT loads, 5-deep batches ----------------
    int sb = bi - NPB;                 // 0..1535
    const float4* s0 = (const float4*)c0;
    const float4* s1 = (const float4*)c1;
    const float4* s2 = (const float4*)c2;
    const float4* s3 = (const float4*)c3;
    const float4* s4 = (const float4*)c4;
    int i = sb * 256 + t;
    float acc0 = 0.0f, acc1 = 0.0f;
    #pragma unroll
    for (int r = 0; r < 2; ++r) {      // iterations 0..9 provably level-0
      f4v v0 = ntload4(s0 + i);
      f4v v1 = ntload4(s0 + i +     SSTRIDE);
      f4v v2 = ntload4(s0 + i + 2 * SSTRIDE);
      f4v v3 = ntload4(s0 + i + 3 * SSTRIDE);
      f4v v4 = ntload4(s0 + i + 4 * SSTRIDE);
      acc0 += negterm4(v0);
      acc1 += negterm4(v1);
      acc0 += negterm4(v2);
      acc1 += negterm4(v3);
      acc0 += negterm4(v4);
      i += 5 * SSTRIDE;
    }
    { // masked tail batch (<=5 more)
      int  j0 = i,               j1 = i + SSTRIDE,     j2 = i + 2 * SSTRIDE;
      int  j3 = i + 3 * SSTRIDE, j4 = i + 4 * SSTRIDE;
      bool m0 = j0 < TOT4, m1 = j1 < TOT4, m2 = j2 < TOT4, m3 = j3 < TOT4, m4 = j4 < TOT4;
      f4v v0 = ntload4(lvl_addr(m0 ? j0 : 0, s0, s1, s2, s3, s4));
      f4v v1 = ntload4(lvl_addr(m1 ? j1 : 0, s0, s1, s2, s3, s4));
      f4v v2 = ntload4(lvl_addr(m2 ? j2 : 0, s0, s1, s2, s3, s4));
      f4v v3 = ntload4(lvl_addr(m3 ? j3 : 0, s0, s1, s2, s3, s4));
      f4v v4 = ntload4(lvl_addr(m4 ? j4 : 0, s0, s1, s2, s3, s4));
      acc0 += m0 ? negterm4(v0) : 0.0f;
      acc1 += m1 ? negterm4(v1) : 0.0f;
      acc0 += m2 ? negterm4(v2) : 0.0f;
      acc1 += m3 ? negterm4(v3) : 0.0f;
      acc0 += m4 ? negterm4(v4) : 0.0f;
    }
    float* sh = (float*)smem;          // 256 floats
    sh[t] = acc0 + acc1;
    __syncthreads();
    #pragma unroll
    for (int off = 128; off > 0; off >>= 1) {
      if (t < off) sh[t] += sh[t + off];
      __syncthreads();
    }
    if (t == 0) {
      astore_u32(&part[sb], __float_as_uint(sh[0]));
      VMCNT0();                        // part durable before counting
      int old = atomicAdd(&ctr[CTR_SUB + (sb & 15)], 1);
      sflag = (old == SUBN - 1);
    }
    __syncthreads();
    if (!sflag) return;

    // ---- subgroup pre-reduce: part[g + 16k], k = 0..95 (fixed order) ----
    int g = sb & 15;
    double* rr = (double*)(smem + 1024);   // 128 doubles
    if (t < 128) {
      double v = 0.0;
      if (t < SUBN) v = (double)__uint_as_float(aload_u32(&part[g + (t << 4)]));
      rr[t] = v;
    }
    __syncthreads();
    #pragma unroll
    for (int off = 64; off > 0; off >>= 1) {
      if (t < off) rr[t] += rr[t + off];
      __syncthreads();
    }
    if (t == 0) {
      astore_u64(&gsum[g], (unsigned long long)__double_as_longlong(rr[0]));
      VMCNT0();
      int old2 = atomicAdd(&ctr[CTR_GLB], 1);
      sflag2 = (old2 == 31);
    }
    __syncthreads();
    if (sflag2) final_combine(bpart, gsum, out, (double*)smem, t);
    return;
  }

  // ---------------- phaseB ----------------
  int blk = bi;
  int b = blk >> 5, g = blk & 31;
  {
    float* sv = (float*)smem;                  // 768 floats
    int*   si = (int*)(smem + 3072);           // 768 ints
    float* tv = (float*)(smem + 6144);         // 256 floats
    int*   ti = (int*)(smem + 7168);           // 256 ints

    float4 GB = gtb[b * NGT + g];
    float c1x = (GB.x + GB.z) * 0.5f, c1y = (GB.y + GB.w) * 0.5f;
    float w1 = GB.z - GB.x + EPSF, h1 = GB.w - GB.y + EPSF;
    float w1s = w1 * w1, h1s = h1 * h1;
    float iw = 1.0f / w1s, ih = 1.0f / h1s;
    float iws = iw + ih;
    float Lg = logf(w1s) + logf(h1s);
    float Ay = 4.0f * ih;
    float Axc = 4.0f * iw;

    float v1[3] = {INFINITY, INFINITY, INFINITY};
    int   i1[3] = {INT_MAX, INT_MAX, INT_MAX};
    float v2 = INFINITY; int i2 = INT_MAX;

    #define DO_LEVEL(BASE, LGW, H, STRIDE, RF) do {                             \
      const int W_ = 1 << (LGW);                                                \
      float w2a = (RF) + 1e-6f;          float w2sa = w2a * w2a;                \
      float w2b = (RF) * 0.9f + 1e-6f;   float w2sb = w2b * w2b;                \
      float K1 = w2sa * iws + Lg - 2.0f * logf(w2sa) - 2.0f;                    \
      float K2 = w2sb * iws + Lg - 2.0f * logf(w2sb) - 2.0f;                    \
      int col = t & (W_ - 1);                                                   \
      float px = (float)(col * (STRIDE) + (STRIDE) / 2);                        \
      float dx = c1x - px;                                                      \
      float kx1 = Axc * dx * dx + K1;                                           \
      float kx2 = Axc * dx * dx + K2;                                           \
      int rstep = 256 >> (LGW);                                                 \
      for (int row = t >> (LGW); row < (H); row += rstep) {                     \
        float py = (float)(row * (STRIDE) + (STRIDE) / 2);                      \
        float dy = c1y - py;                                                    \
        float dy2 = dy * dy;                                                    \
        float k1 = fmaf(Ay, dy2, kx1);                                          \
        float k2 = fmaf(Ay, dy2, kx2);                                          \
        int n = (BASE) + (row << (LGW)) + col;                                  \
        if (k1 < v1[2]) insert3min(v1, i1, k1, n);                              \
        if (k2 < v2) { v2 = k2; i2 = n; }                                       \
      }                                                                         \
    } while (0)

    DO_LEVEL(0,     7, 100,   8,  45.5f);
    DO_LEVEL(12800, 6,  50,  16, 133.5f);
    DO_LEVEL(16000, 5,  25,  32, 213.5f);
    DO_LEVEL(16800, 4,  13,  64, 277.5f);
    DO_LEVEL(17008, 3,   7, 128, 405.5f);
    #undef DO_LEVEL

    sv[t*3+0] = v1[0]; sv[t*3+1] = v1[1]; sv[t*3+2] = v1[2];
    si[t*3+0] = i1[0]; si[t*3+1] = i1[1]; si[t*3+2] = i1[2];
    tv[t] = v2; ti[t] = i2;
    __syncthreads();
    for (int off = 128; off > 0; off >>= 1) {
      if (t < off) {
        #pragma unroll
        for (int k = 0; k < 3; ++k)
          insert3tie(&sv[t * 3], &si[t * 3], sv[(t + off) * 3 + k], si[(t + off) * 3 + k]);
        if (bet(tv[t + off], ti[t + off], tv[t], ti[t])) { tv[t] = tv[t + off]; ti[t] = ti[t + off]; }
      }
      __syncthreads();
    }
    if (t == 0) {
      astore_u32(&win[blk * 4 + 0], (unsigned int)si[0]);
      astore_u32(&win[blk * 4 + 1], (unsigned int)si[1]);
      astore_u32(&win[blk * 4 + 2], (unsigned int)si[2]);
      astore_u32(&win[blk * 4 + 3], (unsigned int)ti[0]);
      VMCNT0();                        // win durable before counting
      int old = atomicAdd(&ctr[CTR_IMG + b], 1);
      sflag = (old == 31);
    }
    __syncthreads();
  }
  if (!sflag) return;

  // ---------------- per-image resolve (overlapped with stream) ----------------
  unsigned int* ukeys = (unsigned int*)smem;   // 128 uints
  double* r0 = (double*)(smem + 512);          // 128 doubles each
  double* r1 = (double*)(smem + 1536);
  double* r2 = (double*)(smem + 2560);
  double* r3 = (double*)(smem + 3584);
  double* r4 = (double*)(smem + 4608);

  if (t < 128) {
    int gg = t >> 2, s = t & 3;
    unsigned int n = aload_u32(&win[b * 128 + gg * 4 + s]);
    unsigned int pri = ((s == 3) ? 32u : 0u) + (unsigned int)gg;
    ukeys[t] = (n << 6) | pri;
  }
  __syncthreads();

  double a_cls = 0.0, a_pos = 0.0, a_ctr = 0.0, a_diou = 0.0, a_cbce = 0.0;

  if (t < 128) {
    unsigned int me = ukeys[t];
    unsigned int nn = me >> 6;
    bool alive = true;
    #pragma unroll 8
    for (int j = 0; j < 128; ++j) {
      unsigned int o = ukeys[j];
      if ((o >> 6) == nn && o > me) alive = false;
    }
    if (alive) {
      int n = (int)nn;
      int gg = (int)(me & 31u);
      int lab = glab[b * NGT + gg];
      float4 gb = gtb[b * NGT + gg];
      Geo G = geom(n);

      const float* bb; const float* ct; const float* cp;
      if (G.lvl == 0)      { bb = bb0; ct = ct0; cp = c0; }
      else if (G.lvl == 1) { bb = bb1; ct = ct1; cp = c1; }
      else if (G.lvl == 2) { bb = bb2; ct = ct2; cp = c2; }
      else if (G.lvl == 3) { bb = bb3; ct = ct3; cp = c3; }
      else                 { bb = bb4; ct = ct4; cp = c4; }

      const float* bp = bb + b * 4 * G.HW + G.j;
      float f0 = bp[0];
      float f1 = bp[G.HW];
      float f2 = bp[2 * G.HW];
      float f3 = bp[3 * G.HW];
      float fo = ct[b * G.HW + G.j];
      float xc = cp[((size_t)(b * 81 + lab)) * G.HW + G.j];

      { // cls correction: posterm - negterm at the target logit
        float ax = fabsf(xc);
        float e  = fexp2(ax * -L2E);
        float r  = frcp(1.0f + e);
        float p  = (xc >= 0.0f) ? r : e * r;
        float sp = fmaxf(xc, 0.0f) + flog2(1.0f + e) * LN2;
        float neg = 0.75f * (p * p) * sp;
        float omp = 1.0f - p;
        float pos = 0.25f * (omp * omp) * (sp - xc);
        a_cls += (double)(pos - neg);
      }

      float tx = G.px - gb.x, ty = G.py - gb.y, tz = gb.z - G.px, tw = gb.w - G.py;

      float lr_min = fminf(tx, tz), lr_max = fmaxf(tx, tz);
      float tb_min = fminf(ty, tw), tb_max = fmaxf(ty, tw);
      float prod = (lr_min / lr_max) * (tb_min / tb_max);
      float ctrt = sqrtf(fmaxf(prod, 0.0f));

      float pb0 = G.px - f0, pb1 = G.py - f1, pb2 = G.px + f2, pb3 = G.py + f3;
      float tb0 = G.px - tx, tb1 = G.py - ty, tb2 = G.px + tz, tb3 = G.py + tw;

      float ltx = fmaxf(pb0, tb0), lty = fmaxf(pb1, tb1);
      float rbx = fminf(pb2, tb2), rby = fminf(pb3, tb3);
      float whx = fmaxf(rbx - ltx, 0.0f), why = fmaxf(rby - lty, 0.0f);
      float ovl = whx * why;
      float ap = (pb2 - pb0) * (pb3 - pb1);
      float ag = (tb2 - tb0) * (tb3 - tb1);
      float ious = ovl / (ap + ag - ovl + EPSF);
      float eltx = fminf(pb0, tb0), elty = fminf(pb1, tb1);
      float erbx = fmaxf(pb2, tb2), erby = fmaxf(pb3, tb3);
      float ewx = fmaxf(erbx - eltx, 0.0f), ewy = fmaxf(erby - elty, 0.0f);
      float c2v = ewx * ewx + ewy * ewy + EPSF;
      float sx = pb0 + pb2 - tb0 - tb2;
      float sy = pb1 + pb3 - tb1 - tb3;
      float rho2 = (sx * sx + sy * sy) * 0.25f;
      float dl = 1.0f - (ious - rho2 / c2v);

      a_pos  += 1.0;
      a_ctr  += (double)ctrt;
      a_diou += (double)(dl * ctrt);
      a_cbce += (double)(fmaxf(fo, 0.0f) - fo * ctrt + log1pf(expf(-fabsf(fo))));
    }
  }

  if (t < 128) { r0[t] = a_cls; r1[t] = a_pos; r2[t] = a_ctr; r3[t] = a_diou; r4[t] = a_cbce; }
  __syncthreads();
  #pragma unroll
  for (int off = 64; off > 0; off >>= 1) {
    if (t < off) {
      r0[t] += r0[t + off]; r1[t] += r1[t + off]; r2[t] += r2[t + off];
      r3[t] += r3[t + off]; r4[t] += r4[t + off];
    }
    __syncthreads();
  }

  if (t == 0) {
    astore_u64(&bpart[b * 5 + 0], (unsigned long long)__double_as_longlong(r0[0]));
    astore_u64(&bpart[b * 5 + 1], (unsigned long long)__double_as_longlong(r1[0]));
    astore_u64(&bpart[b * 5 + 2], (unsigned long long)__double_as_longlong(r2[0]));
    astore_u64(&bpart[b * 5 + 3], (unsigned long long)__double_as_longlong(r3[0]));
    astore_u64(&bpart[b * 5 + 4], (unsigned long long)__double_as_longlong(r4[0]));
    VMCNT0();
    int old2 = atomicAdd(&ctr[CTR_GLB], 1);
    sflag2 = (old2 == 31);
  }
  __syncthreads();
  if (sflag2) final_combine(bpart, gsum, out, (double*)smem, t);
}

extern "C" void kernel_launch(void* const* d_in, const int* in_sizes, int n_in,
                              void* d_out, int out_size, void* d_ws, size_t ws_size,
                              hipStream_t stream) {
  (void)in_sizes; (void)n_in; (void)out_size; (void)ws_size;
  const float* cls[5] = {(const float*)d_in[0],  (const float*)d_in[3],  (const float*)d_in[6],
                         (const float*)d_in[9],  (const float*)d_in[12]};
  const float* bbx[5] = {(const float*)d_in[1],  (const float*)d_in[4],  (const float*)d_in[7],
                         (const float*)d_in[10], (const float*)d_in[13]};
  const float* ctr_[5] = {(const float*)d_in[2],  (const float*)d_in[5],  (const float*)d_in[8],
                          (const float*)d_in[11], (const float*)d_in[14]};
  const float4* gtb = (const float4*)d_in[15];
  const int* glab = (const int*)d_in[16];

  char* ws = (char*)d_ws;
  unsigned int*       win   = (unsigned int*)ws;                     // 2048 u32 = 8192 B
  unsigned int*       part  = (unsigned int*)(ws + 8192);            // 1536 u32 = 6144 B
  unsigned long long* bpart = (unsigned long long*)(ws + 16384);     // 80 u64 = 640 B
  unsigned long long* gsum  = (unsigned long long*)(ws + 17024);     // 16 u64 = 128 B
  int*                cnts  = (int*)(ws + 17152);                    // 33 ints

  zeroK<<<1, 64, 0, stream>>>(cnts);
  fusedK<<<NPB + NSTREAM, 256, 0, stream>>>(
      gtb, glab,
      cls[0], cls[1], cls[2], cls[3], cls[4],
      bbx[0], bbx[1], bbx[2], bbx[3], bbx[4],
      ctr_[0], ctr_[1], ctr_[2], ctr_[3], ctr_[4],
      win, part, bpart, gsum, cnts, (float*)d_out);
}